// Round 2
// baseline (331.559 us; speedup 1.0000x reference)
//
#include <hip/hip_runtime.h>
#include <cstdint>

#define TOKENS 16384
#define DMODEL 512
#define DIM    1024
#define NQ     10
#define NL     2
#define BM     128
#define BN     128
#define BK     32

typedef __bf16 bf16x8 __attribute__((ext_vector_type(8)));
typedef float  f32x4  __attribute__((ext_vector_type(4)));

__device__ __forceinline__ float b2f(unsigned short h) {
    union { unsigned u; float f; } v; v.u = ((unsigned)h) << 16; return v.f;
}
__device__ __forceinline__ unsigned short f2b(float f) {
    unsigned u = __builtin_bit_cast(unsigned, f);
    return (unsigned short)((u + 0x7FFFu + ((u >> 16) & 1u)) >> 16);  // RNE
}
__device__ __forceinline__ float2 cmul(float2 a, float2 b) {
    return make_float2(a.x * b.x - a.y * b.y, a.x * b.y + a.y * b.x);
}
__device__ __forceinline__ float2 cadd(float2 a, float2 b) {
    return make_float2(a.x + b.x, a.y + b.y);
}
__device__ __forceinline__ void async_copy16(const void* g, void* l) {
    __builtin_amdgcn_global_load_lds((const __attribute__((address_space(1))) void*)g,
                                     (__attribute__((address_space(3))) void*)l, 16, 0, 0);
}

// ---------------------------------------------------------------------------
// conv3: fp32 -> bf16 (RNE) for x, W_in, W_out in one grid-stride pass
// ---------------------------------------------------------------------------
__global__ __launch_bounds__(256)
void conv3_kernel(const float* __restrict__ x,  unsigned short* __restrict__ xb,
                  const float* __restrict__ w1, unsigned short* __restrict__ w1b,
                  const float* __restrict__ w2, unsigned short* __restrict__ w2b) {
    const int NX4 = TOKENS * DMODEL / 4;   // 2097152
    const int NW4 = DIM * DMODEL / 4;      // 131072
    const int total = NX4 + 2 * NW4;
    int stride = gridDim.x * blockDim.x;
    for (int i = blockIdx.x * blockDim.x + threadIdx.x; i < total; i += stride) {
        const float* s; unsigned short* d; int j;
        if (i < NX4)            { s = x;  d = xb;  j = i; }
        else if (i < NX4 + NW4) { s = w1; d = w1b; j = i - NX4; }
        else                    { s = w2; d = w2b; j = i - NX4 - NW4; }
        float4 v = *(const float4*)&s[(size_t)j * 4];
        ushort4 o;
        o.x = f2b(v.x); o.y = f2b(v.y); o.z = f2b(v.z); o.w = f2b(v.w);
        *(ushort4*)&d[(size_t)j * 4] = o;
    }
}

// ---------------------------------------------------------------------------
// prep: fuse Rz*Ry*Rx into 2x2 complex gates, precompute CZ diagonal tables
// ---------------------------------------------------------------------------
__global__ void prep_kernel(const float* __restrict__ rot, const float* __restrict__ ent,
                            float2* __restrict__ G, float2* __restrict__ D) {
    const int t = threadIdx.x;
    if (t < NL * NQ) {
        float tx = rot[t * 3 + 0] * 0.5f;
        float ty = rot[t * 3 + 1] * 0.5f;
        float tz = rot[t * 3 + 2] * 0.5f;
        float cx = cosf(tx), sx = sinf(tx);
        float cy = cosf(ty), sy = sinf(ty);
        float cz = cosf(tz), sz = sinf(tz);
        float2 rx00 = make_float2(cx, 0.f),  rx01 = make_float2(0.f, -sx);
        float2 rx10 = make_float2(0.f, -sx), rx11 = make_float2(cx, 0.f);
        float2 ry00 = make_float2(cy, 0.f),  ry01 = make_float2(-sy, 0.f);
        float2 ry10 = make_float2(sy, 0.f),  ry11 = make_float2(cy, 0.f);
        float2 m00 = cadd(cmul(ry00, rx00), cmul(ry01, rx10));
        float2 m01 = cadd(cmul(ry00, rx01), cmul(ry01, rx11));
        float2 m10 = cadd(cmul(ry10, rx00), cmul(ry11, rx10));
        float2 m11 = cadd(cmul(ry10, rx01), cmul(ry11, rx11));
        float2 e0 = make_float2(cz, -sz), e1 = make_float2(cz, sz);
        G[t * 4 + 0] = cmul(e0, m00);
        G[t * 4 + 1] = cmul(e0, m01);
        G[t * 4 + 2] = cmul(e1, m10);
        G[t * 4 + 3] = cmul(e1, m11);
    }
    float ef[NL * (NQ - 1)];
    #pragma unroll
    for (int i = 0; i < NL * (NQ - 1); i++) ef[i] = ent[i];
    for (int e = 0; e < 8; e++) {
        int idx = t + e * 256;        // 0..2047
        int l = idx >> 10, i = idx & (DIM - 1);
        float ang = 0.f;
        #pragma unroll
        for (int q = 0; q < NQ - 1; q++) {
            int both = ((i >> (9 - q)) & 1) & ((i >> (8 - q)) & 1);
            if (both) ang += ef[l * (NQ - 1) + q];
        }
        D[idx] = make_float2(cosf(ang), sinf(ang));
    }
}

// ---------------------------------------------------------------------------
// C[M,N] = A[M,K](bf16) * B[N,K](bf16)^T + bias[N](fp32)
// OUT_BF16: write bf16, else fp32. 128x128x32 tiles, 2x2 waves of 64x64.
// LDS 16B chunks XOR-swizzled by (row>>1)&3 -> 2-way max on ds_read_b128.
// ---------------------------------------------------------------------------
template<bool OUT_BF16>
__global__ __launch_bounds__(256)
void gemm_bt(const unsigned short* __restrict__ A, const unsigned short* __restrict__ B,
             const float* __restrict__ bias, void* __restrict__ Cv,
             int M, int N, int K) {
    __shared__ unsigned short lds_a[BM * BK];
    __shared__ unsigned short lds_b[BN * BK];
    const int t = threadIdx.x;
    const int wave = t >> 6, lane = t & 63;
    const int wm = wave >> 1, wn = wave & 1;
    const int bm0 = blockIdx.y * BM;
    const int bn0 = blockIdx.x * BN;

    f32x4 acc[4][4] = {};

    const int c0 = t, c1 = t + 256;
    const int r0 = c0 >> 2, g0 = (c0 & 3) ^ ((r0 >> 1) & 3);
    const int r1 = c1 >> 2, g1 = (c1 & 3) ^ ((r1 >> 1) & 3);
    char* lbA0 = (char*)lds_a + wave * 1024;
    char* lbA1 = (char*)lds_a + wave * 1024 + 4096;
    char* lbB0 = (char*)lds_b + wave * 1024;
    char* lbB1 = (char*)lds_b + wave * 1024 + 4096;

    for (int k0 = 0; k0 < K; k0 += BK) {
        async_copy16(A + (size_t)(bm0 + r0) * K + k0 + g0 * 8, lbA0);
        async_copy16(A + (size_t)(bm0 + r1) * K + k0 + g1 * 8, lbA1);
        async_copy16(B + (size_t)(bn0 + r0) * K + k0 + g0 * 8, lbB0);
        async_copy16(B + (size_t)(bn0 + r1) * K + k0 + g1 * 8, lbB1);
        __syncthreads();

        bf16x8 af[4], bfr[4];
        #pragma unroll
        for (int i = 0; i < 4; i++) {
            int row = wm * 64 + i * 16 + (lane & 15);
            int slot = (lane >> 4) ^ ((row >> 1) & 3);
            af[i] = *(const bf16x8*)&lds_a[row * BK + slot * 8];
            int nrow = wn * 64 + i * 16 + (lane & 15);
            int nslot = (lane >> 4) ^ ((nrow >> 1) & 3);
            bfr[i] = *(const bf16x8*)&lds_b[nrow * BK + nslot * 8];
        }
        #pragma unroll
        for (int i = 0; i < 4; i++)
            #pragma unroll
            for (int j = 0; j < 4; j++)
                acc[i][j] = __builtin_amdgcn_mfma_f32_16x16x32_bf16(af[i], bfr[j], acc[i][j], 0, 0, 0);
        __syncthreads();
    }

    // C/D layout per m89: col=lane&15, row=(lane>>4)*4+r
    #pragma unroll
    for (int i = 0; i < 4; i++) {
        #pragma unroll
        for (int j = 0; j < 4; j++) {
            int col = bn0 + wn * 64 + j * 16 + (lane & 15);
            float bv = bias[col];
            #pragma unroll
            for (int r = 0; r < 4; r++) {
                int row = bm0 + wm * 64 + i * 16 + (lane >> 4) * 4 + r;
                float val = acc[i][j][r] + bv;
                if (OUT_BF16)
                    ((unsigned short*)Cv)[(size_t)row * N + col] = f2b(val);
                else
                    ((float*)Cv)[(size_t)row * N + col] = val;
            }
        }
    }
}

// ---------------------------------------------------------------------------
// sim: one block per token. L2-normalize bf16 xq row -> psi (LDS, float2,
// padded +1 per 16 to break bank aliasing), 20 fused gates + 2 CZ diagonal
// sweeps, write |psi|^2 bf16 IN PLACE over the row.
// ---------------------------------------------------------------------------
#define PAD(i) ((i) + ((i) >> 4))

__global__ __launch_bounds__(256)
void sim_kernel(unsigned short* __restrict__ xq, const float2* __restrict__ G,
                const float2* __restrict__ D) {
    __shared__ float2 st[DIM + DIM / 16];   // 1088
    __shared__ float red[4];
    __shared__ float2 Us[NL * NQ * 4];
    const int t = threadIdx.x;
    const int tok = blockIdx.x;
    const int lane = t & 63, wave = t >> 6;

    if (t < NL * NQ * 4) Us[t] = G[t];

    ushort4 h = *(const ushort4*)&xq[(size_t)tok * DIM + t * 4];
    float4 v = make_float4(b2f(h.x), b2f(h.y), b2f(h.z), b2f(h.w));
    float ss = v.x * v.x + v.y * v.y + v.z * v.z + v.w * v.w;
    #pragma unroll
    for (int off = 32; off; off >>= 1) ss += __shfl_down(ss, off, 64);
    if (lane == 0) red[wave] = ss;
    __syncthreads();
    ss = red[0] + red[1] + red[2] + red[3];
    float inv = 1.0f / fmaxf(sqrtf(ss), 1e-12f);
    {
        int i = t * 4, a = PAD(i);   // 4 consecutive stay in one 16-group
        st[a + 0] = make_float2(v.x * inv, 0.f);
        st[a + 1] = make_float2(v.y * inv, 0.f);
        st[a + 2] = make_float2(v.z * inv, 0.f);
        st[a + 3] = make_float2(v.w * inv, 0.f);
    }
    __syncthreads();

    for (int l = 0; l < NL; l++) {
        #pragma unroll
        for (int q = 0; q < NQ; q++) {
            const int gi = (l * NQ + q) * 4;
            float2 u00 = Us[gi], u01 = Us[gi + 1], u10 = Us[gi + 2], u11 = Us[gi + 3];
            const int s = 9 - q, S = 1 << s;
            #pragma unroll
            for (int rep = 0; rep < 2; rep++) {
                int p = t + rep * 256;
                int i0 = ((p >> s) << (s + 1)) | (p & (S - 1));
                int i1 = i0 + S;
                float2 a = st[PAD(i0)];
                float2 b = st[PAD(i1)];
                float2 n0, n1;
                n0.x = u00.x * a.x - u00.y * a.y + u01.x * b.x - u01.y * b.y;
                n0.y = u00.x * a.y + u00.y * a.x + u01.x * b.y + u01.y * b.x;
                n1.x = u10.x * a.x - u10.y * a.y + u11.x * b.x - u11.y * b.y;
                n1.y = u10.x * a.y + u10.y * a.x + u11.x * b.y + u11.y * b.x;
                st[PAD(i0)] = n0;
                st[PAD(i1)] = n1;
            }
            __syncthreads();
        }
        #pragma unroll
        for (int rep = 0; rep < 4; rep++) {
            int i = t + rep * 256;
            float2 d = D[l * DIM + i];
            float2 a = st[PAD(i)];
            st[PAD(i)] = make_float2(a.x * d.x - a.y * d.y, a.x * d.y + a.y * d.x);
        }
        __syncthreads();
    }

    {
        int i = t * 4, a = PAD(i);
        float2 a0 = st[a], a1 = st[a + 1], a2 = st[a + 2], a3 = st[a + 3];
        ushort4 o;
        o.x = f2b(a0.x * a0.x + a0.y * a0.y);
        o.y = f2b(a1.x * a1.x + a1.y * a1.y);
        o.z = f2b(a2.x * a2.x + a2.y * a2.y);
        o.w = f2b(a3.x * a3.x + a3.y * a3.y);
        *(ushort4*)&xq[(size_t)tok * DIM + t * 4] = o;
    }
}

// ---------------------------------------------------------------------------
// LayerNorm over DMODEL=512, fp32 in-place on d_out
// ---------------------------------------------------------------------------
__global__ __launch_bounds__(256)
void ln_kernel(float* __restrict__ X, const float* __restrict__ w,
               const float* __restrict__ b) {
    const int t = threadIdx.x;
    const int tok = blockIdx.x;
    const int lane = t & 63, wave = t >> 6;
    __shared__ float redA[4], redB[4];
    float2 v = *(const float2*)&X[(size_t)tok * DMODEL + t * 2];
    float s = v.x + v.y;
    float q = v.x * v.x + v.y * v.y;
    #pragma unroll
    for (int off = 32; off; off >>= 1) {
        s += __shfl_down(s, off, 64);
        q += __shfl_down(q, off, 64);
    }
    if (lane == 0) { redA[wave] = s; redB[wave] = q; }
    __syncthreads();
    s = redA[0] + redA[1] + redA[2] + redA[3];
    q = redB[0] + redB[1] + redB[2] + redB[3];
    float mu = s * (1.0f / DMODEL);
    float var = q * (1.0f / DMODEL) - mu * mu;
    float rstd = rsqrtf(var + 1e-5f);
    float2 o;
    o.x = (v.x - mu) * rstd * w[t * 2] + b[t * 2];
    o.y = (v.y - mu) * rstd * w[t * 2 + 1] + b[t * 2 + 1];
    *(float2*)&X[(size_t)tok * DMODEL + t * 2] = o;
}

extern "C" void kernel_launch(void* const* d_in, const int* in_sizes, int n_in,
                              void* d_out, int out_size, void* d_ws, size_t ws_size,
                              hipStream_t stream) {
    (void)in_sizes; (void)n_in; (void)out_size; (void)ws_size;
    const float* x     = (const float*)d_in[0];   // [16384,512]
    const float* W_in  = (const float*)d_in[1];   // [1024,512]
    const float* b_in  = (const float*)d_in[2];   // [1024]
    const float* W_out = (const float*)d_in[3];   // [512,1024]
    const float* b_out = (const float*)d_in[4];   // [512]
    const float* rot   = (const float*)d_in[5];   // [2,10,3]
    const float* ent   = (const float*)d_in[6];   // [2,9]
    const float* ln_w  = (const float*)d_in[7];   // [512]
    const float* ln_b  = (const float*)d_in[8];   // [512]
    float* out = (float*)d_out;                   // [16384,512] fp32

    char* ws = (char*)d_ws;
    // [0, 32M): xq bf16 [16384][1024]; probs overwrite in place
    // [32M, 48M): x_bf bf16 [16384][512]
    // then W_in bf16 (1MB), W_out bf16 (1MB), G (1KB pad), D (16KB)
    unsigned short* xq   = (unsigned short*)ws;
    unsigned short* x_bf = (unsigned short*)(ws + 33554432ull);
    unsigned short* w1b  = (unsigned short*)(ws + 50331648ull);
    unsigned short* w2b  = (unsigned short*)(ws + 51380224ull);
    float2*         G    = (float2*)(ws + 52428800ull);
    float2*         D    = (float2*)(ws + 52429824ull);
    // high-water: 52,446,208 bytes (~50 MB)

    conv3_kernel<<<2048, 256, 0, stream>>>(x, x_bf, W_in, w1b, W_out, w2b);
    prep_kernel<<<1, 256, 0, stream>>>(rot, ent, G, D);
    gemm_bt<true><<<dim3(DIM / BN, TOKENS / BM), 256, 0, stream>>>(
        x_bf, w1b, b_in, xq, TOKENS, DIM, DMODEL);
    sim_kernel<<<TOKENS, 256, 0, stream>>>(xq, G, D);
    gemm_bt<false><<<dim3(DMODEL / BN, TOKENS / BM), 256, 0, stream>>>(
        xq, w2b, b_out, out, TOKENS, DMODEL, DIM);
    ln_kernel<<<TOKENS, 256, 0, stream>>>(out, ln_w, ln_b);
}

// Round 3
// 299.767 us; speedup vs baseline: 1.1061x; 1.1061x over previous
//
#include <hip/hip_runtime.h>
#include <cstdint>

#define TOKENS 16384
#define DMODEL 512
#define DIM    1024
#define NQ     10
#define NL     2
#define BM     128
#define BN     128
#define BK     32

typedef __bf16 bf16x8 __attribute__((ext_vector_type(8)));
typedef float  f32x4  __attribute__((ext_vector_type(4)));
typedef unsigned short u16x8 __attribute__((ext_vector_type(8)));

__device__ __forceinline__ float b2f(unsigned short h) {
    union { unsigned u; float f; } v; v.u = ((unsigned)h) << 16; return v.f;
}
__device__ __forceinline__ unsigned short f2b(float f) {
    unsigned u = __builtin_bit_cast(unsigned, f);
    return (unsigned short)((u + 0x7FFFu + ((u >> 16) & 1u)) >> 16);  // RNE
}
__device__ __forceinline__ float2 cmul(float2 a, float2 b) {
    return make_float2(a.x * b.x - a.y * b.y, a.x * b.y + a.y * b.x);
}
__device__ __forceinline__ float2 cadd(float2 a, float2 b) {
    return make_float2(a.x + b.x, a.y + b.y);
}
__device__ __forceinline__ void async_copy16(const void* g, void* l) {
    __builtin_amdgcn_global_load_lds((const __attribute__((address_space(1))) void*)g,
                                     (__attribute__((address_space(3))) void*)l, 16, 0, 0);
}

// ---------------------------------------------------------------------------
// conv3: fp32 -> bf16 (RNE) for x, W_in, W_out in one grid-stride pass
// ---------------------------------------------------------------------------
__global__ __launch_bounds__(256)
void conv3_kernel(const float* __restrict__ x,  unsigned short* __restrict__ xb,
                  const float* __restrict__ w1, unsigned short* __restrict__ w1b,
                  const float* __restrict__ w2, unsigned short* __restrict__ w2b) {
    const int NX4 = TOKENS * DMODEL / 4;   // 2097152
    const int NW4 = DIM * DMODEL / 4;      // 131072
    const int total = NX4 + 2 * NW4;
    int stride = gridDim.x * blockDim.x;
    for (int i = blockIdx.x * blockDim.x + threadIdx.x; i < total; i += stride) {
        const float* s; unsigned short* d; int j;
        if (i < NX4)            { s = x;  d = xb;  j = i; }
        else if (i < NX4 + NW4) { s = w1; d = w1b; j = i - NX4; }
        else                    { s = w2; d = w2b; j = i - NX4 - NW4; }
        float4 v = *(const float4*)&s[(size_t)j * 4];
        ushort4 o;
        o.x = f2b(v.x); o.y = f2b(v.y); o.z = f2b(v.z); o.w = f2b(v.w);
        *(ushort4*)&d[(size_t)j * 4] = o;
    }
}

// ---------------------------------------------------------------------------
// prep: fuse Rz*Ry*Rx into 2x2 complex gates, precompute CZ diagonal tables
// Dt stored LANE-TRANSPOSED for the register-resident sim:
//   Dt[l*1024 + (amp&15)*64 + (amp>>4)] = exp(i*phase(l, amp))
// ---------------------------------------------------------------------------
__global__ void prep_kernel(const float* __restrict__ rot, const float* __restrict__ ent,
                            float2* __restrict__ G, float2* __restrict__ Dt) {
    const int t = threadIdx.x;
    if (t < NL * NQ) {
        float tx = rot[t * 3 + 0] * 0.5f;
        float ty = rot[t * 3 + 1] * 0.5f;
        float tz = rot[t * 3 + 2] * 0.5f;
        float cx = cosf(tx), sx = sinf(tx);
        float cy = cosf(ty), sy = sinf(ty);
        float cz = cosf(tz), sz = sinf(tz);
        float2 rx00 = make_float2(cx, 0.f),  rx01 = make_float2(0.f, -sx);
        float2 rx10 = make_float2(0.f, -sx), rx11 = make_float2(cx, 0.f);
        float2 ry00 = make_float2(cy, 0.f),  ry01 = make_float2(-sy, 0.f);
        float2 ry10 = make_float2(sy, 0.f),  ry11 = make_float2(cy, 0.f);
        float2 m00 = cadd(cmul(ry00, rx00), cmul(ry01, rx10));
        float2 m01 = cadd(cmul(ry00, rx01), cmul(ry01, rx11));
        float2 m10 = cadd(cmul(ry10, rx00), cmul(ry11, rx10));
        float2 m11 = cadd(cmul(ry10, rx01), cmul(ry11, rx11));
        float2 e0 = make_float2(cz, -sz), e1 = make_float2(cz, sz);
        G[t * 4 + 0] = cmul(e0, m00);
        G[t * 4 + 1] = cmul(e0, m01);
        G[t * 4 + 2] = cmul(e1, m10);
        G[t * 4 + 3] = cmul(e1, m11);
    }
    float ef[NL * (NQ - 1)];
    #pragma unroll
    for (int i = 0; i < NL * (NQ - 1); i++) ef[i] = ent[i];
    for (int e = 0; e < 8; e++) {
        int idx = t + e * 256;        // 0..2047
        int l = idx >> 10, amp = idx & (DIM - 1);
        float ang = 0.f;
        #pragma unroll
        for (int q = 0; q < NQ - 1; q++) {
            int both = ((amp >> (9 - q)) & 1) & ((amp >> (8 - q)) & 1);
            if (both) ang += ef[l * (NQ - 1) + q];
        }
        Dt[l * DIM + (amp & 15) * 64 + (amp >> 4)] = make_float2(cosf(ang), sinf(ang));
    }
}

// ---------------------------------------------------------------------------
// C[M,N] = A[M,K](bf16) * B[N,K](bf16)^T + bias[N](fp32)
// OUT_BF16: write bf16, else fp32. 128x128x32 tiles, 2x2 waves of 64x64.
// ---------------------------------------------------------------------------
template<bool OUT_BF16>
__global__ __launch_bounds__(256)
void gemm_bt(const unsigned short* __restrict__ A, const unsigned short* __restrict__ B,
             const float* __restrict__ bias, void* __restrict__ Cv,
             int M, int N, int K) {
    __shared__ unsigned short lds_a[BM * BK];
    __shared__ unsigned short lds_b[BN * BK];
    const int t = threadIdx.x;
    const int wave = t >> 6, lane = t & 63;
    const int wm = wave >> 1, wn = wave & 1;
    const int bm0 = blockIdx.y * BM;
    const int bn0 = blockIdx.x * BN;

    f32x4 acc[4][4] = {};

    const int c0 = t, c1 = t + 256;
    const int r0 = c0 >> 2, g0 = (c0 & 3) ^ ((r0 >> 1) & 3);
    const int r1 = c1 >> 2, g1 = (c1 & 3) ^ ((r1 >> 1) & 3);
    char* lbA0 = (char*)lds_a + wave * 1024;
    char* lbA1 = (char*)lds_a + wave * 1024 + 4096;
    char* lbB0 = (char*)lds_b + wave * 1024;
    char* lbB1 = (char*)lds_b + wave * 1024 + 4096;

    for (int k0 = 0; k0 < K; k0 += BK) {
        async_copy16(A + (size_t)(bm0 + r0) * K + k0 + g0 * 8, lbA0);
        async_copy16(A + (size_t)(bm0 + r1) * K + k0 + g1 * 8, lbA1);
        async_copy16(B + (size_t)(bn0 + r0) * K + k0 + g0 * 8, lbB0);
        async_copy16(B + (size_t)(bn0 + r1) * K + k0 + g1 * 8, lbB1);
        __syncthreads();

        bf16x8 af[4], bfr[4];
        #pragma unroll
        for (int i = 0; i < 4; i++) {
            int row = wm * 64 + i * 16 + (lane & 15);
            int slot = (lane >> 4) ^ ((row >> 1) & 3);
            af[i] = *(const bf16x8*)&lds_a[row * BK + slot * 8];
            int nrow = wn * 64 + i * 16 + (lane & 15);
            int nslot = (lane >> 4) ^ ((nrow >> 1) & 3);
            bfr[i] = *(const bf16x8*)&lds_b[nrow * BK + nslot * 8];
        }
        #pragma unroll
        for (int i = 0; i < 4; i++)
            #pragma unroll
            for (int j = 0; j < 4; j++)
                acc[i][j] = __builtin_amdgcn_mfma_f32_16x16x32_bf16(af[i], bfr[j], acc[i][j], 0, 0, 0);
        __syncthreads();
    }

    // C/D layout per m89: col=lane&15, row=(lane>>4)*4+r
    #pragma unroll
    for (int i = 0; i < 4; i++) {
        #pragma unroll
        for (int j = 0; j < 4; j++) {
            int col = bn0 + wn * 64 + j * 16 + (lane & 15);
            float bv = bias[col];
            #pragma unroll
            for (int r = 0; r < 4; r++) {
                int row = bm0 + wm * 64 + i * 16 + (lane >> 4) * 4 + r;
                float val = acc[i][j][r] + bv;
                if (OUT_BF16)
                    ((unsigned short*)Cv)[(size_t)row * N + col] = f2b(val);
                else
                    ((float*)Cv)[(size_t)row * N + col] = val;
            }
        }
    }
}

// ---------------------------------------------------------------------------
// sim: ONE WAVE PER TOKEN, statevector register-resident.
// amp index = lane*16 + r  (lane = amp bits b9..b4, r = bits b3..b0).
// Qubits 0..5  -> lane-bit gates via __shfl_xor (masks 32,16,8,4,2,1).
// Qubits 6..9  -> register gates (pair strides 8,4,2,1 within amp[16]).
// CZ diagonal  -> coalesced loads from lane-transposed Dt.
// No LDS data traffic, no __syncthreads, no bank conflicts.
// ---------------------------------------------------------------------------
__global__ __launch_bounds__(256)
void sim_kernel(unsigned short* __restrict__ xq, const float2* __restrict__ G,
                const float2* __restrict__ Dt) {
    const int t = threadIdx.x;
    const int lane = t & 63;
    const int tok = blockIdx.x * 4 + (t >> 6);

    unsigned short* row = xq + (size_t)tok * DIM + lane * 16;
    u16x8 h0 = *(const u16x8*)row;
    u16x8 h1 = *(const u16x8*)(row + 8);
    float2 amp[16];
    #pragma unroll
    for (int r = 0; r < 8; r++) amp[r]     = make_float2(b2f((unsigned short)h0[r]), 0.f);
    #pragma unroll
    for (int r = 0; r < 8; r++) amp[r + 8] = make_float2(b2f((unsigned short)h1[r]), 0.f);

    // L2 norm across the wave
    float ss = 0.f;
    #pragma unroll
    for (int r = 0; r < 16; r++) ss += amp[r].x * amp[r].x;
    #pragma unroll
    for (int m = 1; m < 64; m <<= 1) ss += __shfl_xor(ss, m, 64);
    float inv = 1.0f / fmaxf(sqrtf(ss), 1e-12f);
    #pragma unroll
    for (int r = 0; r < 16; r++) amp[r].x *= inv;

    #pragma unroll 1   // keep layer loop rolled: halves I$ footprint
    for (int l = 0; l < NL; l++) {
        const float2* Gl = G + (size_t)l * NQ * 4;
        // lane-bit gates: qubit q has amp-bit b(9-q) = lane bit (5-q)
        #pragma unroll
        for (int q = 0; q < 6; q++) {
            float2 u00 = Gl[q * 4 + 0], u01 = Gl[q * 4 + 1];
            float2 u10 = Gl[q * 4 + 2], u11 = Gl[q * 4 + 3];
            const int mask = 32 >> q;
            int bit = (lane >> (5 - q)) & 1;
            // my new value: bit==0: n = u00*a + u01*p ; bit==1: n = u11*a + u10*p
            float2 ua = bit ? u11 : u00;
            float2 ub = bit ? u10 : u01;
            #pragma unroll
            for (int r = 0; r < 16; r++) {
                float px = __shfl_xor(amp[r].x, mask, 64);
                float py = __shfl_xor(amp[r].y, mask, 64);
                float nx = ua.x * amp[r].x - ua.y * amp[r].y + ub.x * px - ub.y * py;
                float ny = ua.x * amp[r].y + ua.y * amp[r].x + ub.x * py + ub.y * px;
                amp[r] = make_float2(nx, ny);
            }
        }
        // register gates: qubit q (6..9), pair stride S = 1<<(9-q) in r
        #pragma unroll
        for (int q = 6; q < 10; q++) {
            float2 u00 = Gl[q * 4 + 0], u01 = Gl[q * 4 + 1];
            float2 u10 = Gl[q * 4 + 2], u11 = Gl[q * 4 + 3];
            const int S = 1 << (9 - q);
            #pragma unroll
            for (int r = 0; r < 16; r++) {
                if (r & S) continue;   // compile-time pruned
                float2 a = amp[r], b = amp[r + S];
                float2 n0, n1;
                n0.x = u00.x * a.x - u00.y * a.y + u01.x * b.x - u01.y * b.y;
                n0.y = u00.x * a.y + u00.y * a.x + u01.x * b.y + u01.y * b.x;
                n1.x = u10.x * a.x - u10.y * a.y + u11.x * b.x - u11.y * b.y;
                n1.y = u10.x * a.y + u10.y * a.x + u11.x * b.y + u11.y * b.x;
                amp[r] = n0;
                amp[r + S] = n1;
            }
        }
        // CZ diagonal: coalesced (lanes consecutive)
        #pragma unroll
        for (int r = 0; r < 16; r++) {
            float2 d = Dt[(size_t)l * DIM + r * 64 + lane];
            amp[r] = cmul(amp[r], d);
        }
    }

    u16x8 o0, o1;
    #pragma unroll
    for (int r = 0; r < 8; r++)
        o0[r] = f2b(amp[r].x * amp[r].x + amp[r].y * amp[r].y);
    #pragma unroll
    for (int r = 0; r < 8; r++)
        o1[r] = f2b(amp[r + 8].x * amp[r + 8].x + amp[r + 8].y * amp[r + 8].y);
    *(u16x8*)row = o0;
    *(u16x8*)(row + 8) = o1;
}

// ---------------------------------------------------------------------------
// LayerNorm over DMODEL=512, fp32 in-place on d_out
// ---------------------------------------------------------------------------
__global__ __launch_bounds__(256)
void ln_kernel(float* __restrict__ X, const float* __restrict__ w,
               const float* __restrict__ b) {
    const int t = threadIdx.x;
    const int tok = blockIdx.x;
    const int lane = t & 63, wave = t >> 6;
    __shared__ float redA[4], redB[4];
    float2 v = *(const float2*)&X[(size_t)tok * DMODEL + t * 2];
    float s = v.x + v.y;
    float q = v.x * v.x + v.y * v.y;
    #pragma unroll
    for (int off = 32; off; off >>= 1) {
        s += __shfl_down(s, off, 64);
        q += __shfl_down(q, off, 64);
    }
    if (lane == 0) { redA[wave] = s; redB[wave] = q; }
    __syncthreads();
    s = redA[0] + redA[1] + redA[2] + redA[3];
    q = redB[0] + redB[1] + redB[2] + redB[3];
    float mu = s * (1.0f / DMODEL);
    float var = q * (1.0f / DMODEL) - mu * mu;
    float rstd = rsqrtf(var + 1e-5f);
    float2 o;
    o.x = (v.x - mu) * rstd * w[t * 2] + b[t * 2];
    o.y = (v.y - mu) * rstd * w[t * 2 + 1] + b[t * 2 + 1];
    *(float2*)&X[(size_t)tok * DMODEL + t * 2] = o;
}

extern "C" void kernel_launch(void* const* d_in, const int* in_sizes, int n_in,
                              void* d_out, int out_size, void* d_ws, size_t ws_size,
                              hipStream_t stream) {
    (void)in_sizes; (void)n_in; (void)out_size; (void)ws_size;
    const float* x     = (const float*)d_in[0];   // [16384,512]
    const float* W_in  = (const float*)d_in[1];   // [1024,512]
    const float* b_in  = (const float*)d_in[2];   // [1024]
    const float* W_out = (const float*)d_in[3];   // [512,1024]
    const float* b_out = (const float*)d_in[4];   // [512]
    const float* rot   = (const float*)d_in[5];   // [2,10,3]
    const float* ent   = (const float*)d_in[6];   // [2,9]
    const float* ln_w  = (const float*)d_in[7];   // [512]
    const float* ln_b  = (const float*)d_in[8];   // [512]
    float* out = (float*)d_out;                   // [16384,512] fp32

    char* ws = (char*)d_ws;
    unsigned short* xq   = (unsigned short*)ws;                   // 32 MB
    unsigned short* x_bf = (unsigned short*)(ws + 33554432ull);   // 16 MB
    unsigned short* w1b  = (unsigned short*)(ws + 50331648ull);   // 1 MB
    unsigned short* w2b  = (unsigned short*)(ws + 51380224ull);   // 1 MB
    float2*         G    = (float2*)(ws + 52428800ull);           // 640 B (1 KB pad)
    float2*         Dt   = (float2*)(ws + 52429824ull);           // 16 KB
    // high-water: ~50 MB

    conv3_kernel<<<2048, 256, 0, stream>>>(x, x_bf, W_in, w1b, W_out, w2b);
    prep_kernel<<<1, 256, 0, stream>>>(rot, ent, G, Dt);
    gemm_bt<true><<<dim3(DIM / BN, TOKENS / BM), 256, 0, stream>>>(
        x_bf, w1b, b_in, xq, TOKENS, DIM, DMODEL);
    sim_kernel<<<TOKENS / 4, 256, 0, stream>>>(xq, G, Dt);
    gemm_bt<false><<<dim3(DMODEL / BN, TOKENS / BM), 256, 0, stream>>>(
        xq, w2b, b_out, out, TOKENS, DMODEL, DIM);
    ln_kernel<<<TOKENS, 256, 0, stream>>>(out, ln_w, ln_b);
}

// Round 4
// 259.079 us; speedup vs baseline: 1.2798x; 1.1570x over previous
//
#include <hip/hip_runtime.h>
#include <cstdint>

#define TOKENS 16384
#define DMODEL 512
#define DIM    1024
#define NQ     10
#define NL     2
#define BM     128
#define BN     128
#define BK     32

typedef __bf16 bf16x8 __attribute__((ext_vector_type(8)));
typedef float  f32x4  __attribute__((ext_vector_type(4)));
typedef unsigned short u16x8 __attribute__((ext_vector_type(8)));

__device__ __forceinline__ float b2f(unsigned short h) {
    union { unsigned u; float f; } v; v.u = ((unsigned)h) << 16; return v.f;
}
__device__ __forceinline__ unsigned short f2b(float f) {
    unsigned u = __builtin_bit_cast(unsigned, f);
    return (unsigned short)((u + 0x7FFFu + ((u >> 16) & 1u)) >> 16);  // RNE
}
__device__ __forceinline__ float2 cmul(float2 a, float2 b) {
    return make_float2(a.x * b.x - a.y * b.y, a.x * b.y + a.y * b.x);
}
__device__ __forceinline__ float2 cadd(float2 a, float2 b) {
    return make_float2(a.x + b.x, a.y + b.y);
}
__device__ __forceinline__ void async_copy16(const void* g, void* l) {
    __builtin_amdgcn_global_load_lds((const __attribute__((address_space(1))) void*)g,
                                     (__attribute__((address_space(3))) void*)l, 16, 0, 0);
}

// ---------------------------------------------------------------------------
// conv2: fp32 -> bf16 for x and W_out
// ---------------------------------------------------------------------------
__global__ __launch_bounds__(256)
void conv2_kernel(const float* __restrict__ x,  unsigned short* __restrict__ xb,
                  const float* __restrict__ w2, unsigned short* __restrict__ w2b) {
    const int NX4 = TOKENS * DMODEL / 4;   // 2097152
    const int NW4 = DMODEL * DIM / 4;      // 131072
    const int total = NX4 + NW4;
    int stride = gridDim.x * blockDim.x;
    for (int i = blockIdx.x * blockDim.x + threadIdx.x; i < total; i += stride) {
        const float* s; unsigned short* d; int j;
        if (i < NX4) { s = x;  d = xb;  j = i; }
        else         { s = w2; d = w2b; j = i - NX4; }
        float4 v = *(const float4*)&s[(size_t)j * 4];
        ushort4 o;
        o.x = f2b(v.x); o.y = f2b(v.y); o.z = f2b(v.z); o.w = f2b(v.w);
        *(ushort4*)&d[(size_t)j * 4] = o;
    }
}

// ---------------------------------------------------------------------------
// tpose: W_in [1024,512] fp32 -> Wt [512,1024] bf16 (transposed)
// ---------------------------------------------------------------------------
__global__ __launch_bounds__(256)
void tpose_kernel(const float* __restrict__ W, unsigned short* __restrict__ Wt) {
    __shared__ float tile[32][33];
    const int tx = threadIdx.x & 31, ty = threadIdx.x >> 5;   // 32x8
    const int j0 = blockIdx.y * 32, d0 = blockIdx.x * 32;
    #pragma unroll
    for (int i = 0; i < 32; i += 8)
        tile[ty + i][tx] = W[(size_t)(j0 + ty + i) * DMODEL + d0 + tx];
    __syncthreads();
    #pragma unroll
    for (int i = 0; i < 32; i += 8)
        Wt[(size_t)(d0 + ty + i) * DIM + j0 + tx] = f2b(tile[tx][ty + i]);
}

// ---------------------------------------------------------------------------
// prep: fuse Rz*Ry*Rx into 2x2 complex gates, CZ diagonal lane-transposed:
//   Dt[l*1024 + (amp&15)*64 + (amp>>4)]
// ---------------------------------------------------------------------------
__global__ void prep_kernel(const float* __restrict__ rot, const float* __restrict__ ent,
                            float2* __restrict__ G, float2* __restrict__ Dt) {
    const int t = threadIdx.x;
    if (t < NL * NQ) {
        float tx = rot[t * 3 + 0] * 0.5f;
        float ty = rot[t * 3 + 1] * 0.5f;
        float tz = rot[t * 3 + 2] * 0.5f;
        float cx = cosf(tx), sx = sinf(tx);
        float cy = cosf(ty), sy = sinf(ty);
        float cz = cosf(tz), sz = sinf(tz);
        float2 rx00 = make_float2(cx, 0.f),  rx01 = make_float2(0.f, -sx);
        float2 rx10 = make_float2(0.f, -sx), rx11 = make_float2(cx, 0.f);
        float2 ry00 = make_float2(cy, 0.f),  ry01 = make_float2(-sy, 0.f);
        float2 ry10 = make_float2(sy, 0.f),  ry11 = make_float2(cy, 0.f);
        float2 m00 = cadd(cmul(ry00, rx00), cmul(ry01, rx10));
        float2 m01 = cadd(cmul(ry00, rx01), cmul(ry01, rx11));
        float2 m10 = cadd(cmul(ry10, rx00), cmul(ry11, rx10));
        float2 m11 = cadd(cmul(ry10, rx01), cmul(ry11, rx11));
        float2 e0 = make_float2(cz, -sz), e1 = make_float2(cz, sz);
        G[t * 4 + 0] = cmul(e0, m00);
        G[t * 4 + 1] = cmul(e0, m01);
        G[t * 4 + 2] = cmul(e1, m10);
        G[t * 4 + 3] = cmul(e1, m11);
    }
    float ef[NL * (NQ - 1)];
    #pragma unroll
    for (int i = 0; i < NL * (NQ - 1); i++) ef[i] = ent[i];
    for (int e = 0; e < 8; e++) {
        int idx = t + e * 256;
        int l = idx >> 10, amp = idx & (DIM - 1);
        float ang = 0.f;
        #pragma unroll
        for (int q = 0; q < NQ - 1; q++) {
            int both = ((amp >> (9 - q)) & 1) & ((amp >> (8 - q)) & 1);
            if (both) ang += ef[l * (NQ - 1) + q];
        }
        Dt[l * DIM + (amp & 15) * 64 + (amp >> 4)] = make_float2(cosf(ang), sinf(ang));
    }
}

// ---------------------------------------------------------------------------
// buildU: one wave per row c. Applies the TRANSPOSED circuit (layers in
// reverse, D first, gates q=9..0 with u01<->u10 swapped) to basis state e_c,
// yielding row c of U. Stores Ucat[c][k]=Re U[c,k], Ucat[c+1024][k]=Im.
// ---------------------------------------------------------------------------
__global__ __launch_bounds__(256)
void buildU_kernel(const float2* __restrict__ G, const float2* __restrict__ Dt,
                   unsigned short* __restrict__ U) {
    const int t = threadIdx.x, lane = t & 63;
    const int c = blockIdx.x * 4 + (t >> 6);

    float2 amp[16];
    #pragma unroll
    for (int r = 0; r < 16; r++)
        amp[r] = make_float2((lane * 16 + r == c) ? 1.f : 0.f, 0.f);

    #pragma unroll 1
    for (int li = 0; li < NL; li++) {
        const int l = NL - 1 - li;
        #pragma unroll
        for (int r = 0; r < 16; r++)
            amp[r] = cmul(amp[r], Dt[(size_t)l * DIM + r * 64 + lane]);
        const float2* Gl = G + (size_t)l * NQ * 4;
        #pragma unroll
        for (int qq = 0; qq < NQ; qq++) {
            const int q = 9 - qq;
            float2 u00 = Gl[q * 4 + 0], u10 = Gl[q * 4 + 1];   // swapped:
            float2 u01 = Gl[q * 4 + 2], u11 = Gl[q * 4 + 3];   // u01<->u10
            if (q >= 6) {
                const int S = 1 << (9 - q);
                #pragma unroll
                for (int r = 0; r < 16; r++) {
                    if (r & S) continue;
                    float2 a = amp[r], b = amp[r + S];
                    float2 n0, n1;
                    n0.x = u00.x * a.x - u00.y * a.y + u01.x * b.x - u01.y * b.y;
                    n0.y = u00.x * a.y + u00.y * a.x + u01.x * b.y + u01.y * b.x;
                    n1.x = u10.x * a.x - u10.y * a.y + u11.x * b.x - u11.y * b.y;
                    n1.y = u10.x * a.y + u10.y * a.x + u11.x * b.y + u11.y * b.x;
                    amp[r] = n0; amp[r + S] = n1;
                }
            } else {
                const int mask = 32 >> q;
                int bit = (lane >> (5 - q)) & 1;
                float2 ua = bit ? u11 : u00;
                float2 ub = bit ? u10 : u01;
                #pragma unroll
                for (int r = 0; r < 16; r++) {
                    float px = __shfl_xor(amp[r].x, mask, 64);
                    float py = __shfl_xor(amp[r].y, mask, 64);
                    float nx = ua.x * amp[r].x - ua.y * amp[r].y + ub.x * px - ub.y * py;
                    float ny = ua.x * amp[r].y + ua.y * amp[r].x + ub.x * py + ub.y * px;
                    amp[r] = make_float2(nx, ny);
                }
            }
        }
    }

    u16x8 o0, o1, p0, p1;
    #pragma unroll
    for (int r = 0; r < 8; r++) {
        o0[r] = f2b(amp[r].x);     o1[r] = f2b(amp[r + 8].x);
        p0[r] = f2b(amp[r].y);     p1[r] = f2b(amp[r + 8].y);
    }
    unsigned short* rowRe = U + (size_t)c * DIM + lane * 16;
    unsigned short* rowIm = U + (size_t)(c + DIM) * DIM + lane * 16;
    *(u16x8*)rowRe = o0; *(u16x8*)(rowRe + 8) = o1;
    *(u16x8*)rowIm = p0; *(u16x8*)(rowIm + 8) = p1;
}

// ---------------------------------------------------------------------------
// foldB: b2[j] = sum_k Ucat[j,k] * b_in[k], one wave per j
// ---------------------------------------------------------------------------
__global__ __launch_bounds__(256)
void foldb_kernel(const unsigned short* __restrict__ U, const float* __restrict__ bin,
                  float* __restrict__ b2) {
    const int lane = threadIdx.x & 63;
    const int j = blockIdx.x * 4 + (threadIdx.x >> 6);
    const unsigned short* row = U + (size_t)j * DIM;
    float acc = 0.f;
    #pragma unroll
    for (int i = 0; i < 16; i++) {
        int k = lane + i * 64;
        acc += b2f(row[k]) * bin[k];
    }
    #pragma unroll
    for (int m = 1; m < 64; m <<= 1) acc += __shfl_xor(acc, m, 64);
    if (lane == 0) b2[j] = acc;
}

// ---------------------------------------------------------------------------
// C[M,N] = A[M,K](bf16, row stride lda) * B[N,K](bf16)^T (+ bias[N] fp32)
// 128x128x32 tiles, 2x2 waves of 64x64, mfma 16x16x32 bf16.
// ---------------------------------------------------------------------------
template<bool OUT_BF16, bool HAS_BIAS>
__global__ __launch_bounds__(256)
void gemm_bt(const unsigned short* __restrict__ A, const unsigned short* __restrict__ B,
             const float* __restrict__ bias, void* __restrict__ Cv,
             int M, int N, int K, int lda) {
    __shared__ unsigned short lds_a[BM * BK];
    __shared__ unsigned short lds_b[BN * BK];
    const int t = threadIdx.x;
    const int wave = t >> 6, lane = t & 63;
    const int wm = wave >> 1, wn = wave & 1;
    const int bm0 = blockIdx.y * BM;
    const int bn0 = blockIdx.x * BN;

    f32x4 acc[4][4] = {};

    const int c0 = t, c1 = t + 256;
    const int r0 = c0 >> 2, g0 = (c0 & 3) ^ ((r0 >> 1) & 3);
    const int r1 = c1 >> 2, g1 = (c1 & 3) ^ ((r1 >> 1) & 3);
    char* lbA0 = (char*)lds_a + wave * 1024;
    char* lbA1 = (char*)lds_a + wave * 1024 + 4096;
    char* lbB0 = (char*)lds_b + wave * 1024;
    char* lbB1 = (char*)lds_b + wave * 1024 + 4096;

    for (int k0 = 0; k0 < K; k0 += BK) {
        async_copy16(A + (size_t)(bm0 + r0) * lda + k0 + g0 * 8, lbA0);
        async_copy16(A + (size_t)(bm0 + r1) * lda + k0 + g1 * 8, lbA1);
        async_copy16(B + (size_t)(bn0 + r0) * K + k0 + g0 * 8, lbB0);
        async_copy16(B + (size_t)(bn0 + r1) * K + k0 + g1 * 8, lbB1);
        __syncthreads();

        bf16x8 af[4], bfr[4];
        #pragma unroll
        for (int i = 0; i < 4; i++) {
            int row = wm * 64 + i * 16 + (lane & 15);
            int slot = (lane >> 4) ^ ((row >> 1) & 3);
            af[i] = *(const bf16x8*)&lds_a[row * BK + slot * 8];
            int nrow = wn * 64 + i * 16 + (lane & 15);
            int nslot = (lane >> 4) ^ ((nrow >> 1) & 3);
            bfr[i] = *(const bf16x8*)&lds_b[nrow * BK + nslot * 8];
        }
        #pragma unroll
        for (int i = 0; i < 4; i++)
            #pragma unroll
            for (int j = 0; j < 4; j++)
                acc[i][j] = __builtin_amdgcn_mfma_f32_16x16x32_bf16(af[i], bfr[j], acc[i][j], 0, 0, 0);
        __syncthreads();
    }

    #pragma unroll
    for (int i = 0; i < 4; i++) {
        #pragma unroll
        for (int j = 0; j < 4; j++) {
            int col = bn0 + wn * 64 + j * 16 + (lane & 15);
            float bv = HAS_BIAS ? bias[col] : 0.f;
            #pragma unroll
            for (int r = 0; r < 4; r++) {
                int row = bm0 + wm * 64 + i * 16 + (lane >> 4) * 4 + r;
                float val = acc[i][j][r] + bv;
                if (OUT_BF16)
                    ((unsigned short*)Cv)[(size_t)row * N + col] = f2b(val);
                else
                    ((float*)Cv)[(size_t)row * N + col] = val;
            }
        }
    }
}

// ---------------------------------------------------------------------------
// sqnorm: one wave per token. n2 = sum over row (re^2+im^2); by unitarity
// n2 == ||xq||^2. probs[k] = (re_k^2+im_k^2)/max(n2,1e-24), written in place
// over the re half (row stride stays 2048 for GEMM2's lda).
// ---------------------------------------------------------------------------
__global__ __launch_bounds__(256)
void sqnorm_kernel(unsigned short* __restrict__ y) {
    const int lane = threadIdx.x & 63;
    const int tok = blockIdx.x * 4 + (threadIdx.x >> 6);
    unsigned short* row = y + (size_t)tok * (2 * DIM) + lane * 16;
    u16x8 a0 = *(const u16x8*)row;
    u16x8 a1 = *(const u16x8*)(row + 8);
    u16x8 c0 = *(const u16x8*)(row + DIM);
    u16x8 c1 = *(const u16x8*)(row + DIM + 8);
    float p[16];
    float n2 = 0.f;
    #pragma unroll
    for (int r = 0; r < 8; r++) {
        float re = b2f((unsigned short)a0[r]), im = b2f((unsigned short)c0[r]);
        p[r] = re * re + im * im; n2 += p[r];
    }
    #pragma unroll
    for (int r = 0; r < 8; r++) {
        float re = b2f((unsigned short)a1[r]), im = b2f((unsigned short)c1[r]);
        p[r + 8] = re * re + im * im; n2 += p[r + 8];
    }
    #pragma unroll
    for (int m = 1; m < 64; m <<= 1) n2 += __shfl_xor(n2, m, 64);
    float inv = 1.0f / fmaxf(n2, 1e-24f);
    u16x8 o0, o1;
    #pragma unroll
    for (int r = 0; r < 8; r++) { o0[r] = f2b(p[r] * inv); o1[r] = f2b(p[r + 8] * inv); }
    *(u16x8*)row = o0;
    *(u16x8*)(row + 8) = o1;
}

// ---------------------------------------------------------------------------
// LayerNorm over DMODEL=512, fp32 in-place on d_out
// ---------------------------------------------------------------------------
__global__ __launch_bounds__(256)
void ln_kernel(float* __restrict__ X, const float* __restrict__ w,
               const float* __restrict__ b) {
    const int t = threadIdx.x;
    const int tok = blockIdx.x;
    const int lane = t & 63, wave = t >> 6;
    __shared__ float redA[4], redB[4];
    float2 v = *(const float2*)&X[(size_t)tok * DMODEL + t * 2];
    float s = v.x + v.y;
    float q = v.x * v.x + v.y * v.y;
    #pragma unroll
    for (int off = 32; off; off >>= 1) {
        s += __shfl_down(s, off, 64);
        q += __shfl_down(q, off, 64);
    }
    if (lane == 0) { redA[wave] = s; redB[wave] = q; }
    __syncthreads();
    s = redA[0] + redA[1] + redA[2] + redA[3];
    q = redB[0] + redB[1] + redB[2] + redB[3];
    float mu = s * (1.0f / DMODEL);
    float var = q * (1.0f / DMODEL) - mu * mu;
    float rstd = rsqrtf(var + 1e-5f);
    float2 o;
    o.x = (v.x - mu) * rstd * w[t * 2] + b[t * 2];
    o.y = (v.y - mu) * rstd * w[t * 2 + 1] + b[t * 2 + 1];
    *(float2*)&X[(size_t)tok * DMODEL + t * 2] = o;
}

extern "C" void kernel_launch(void* const* d_in, const int* in_sizes, int n_in,
                              void* d_out, int out_size, void* d_ws, size_t ws_size,
                              hipStream_t stream) {
    (void)in_sizes; (void)n_in; (void)out_size; (void)ws_size;
    const float* x     = (const float*)d_in[0];
    const float* W_in  = (const float*)d_in[1];
    const float* b_in  = (const float*)d_in[2];
    const float* W_out = (const float*)d_in[3];
    const float* b_out = (const float*)d_in[4];
    const float* rot   = (const float*)d_in[5];
    const float* ent   = (const float*)d_in[6];
    const float* ln_w  = (const float*)d_in[7];
    const float* ln_b  = (const float*)d_in[8];
    float* out = (float*)d_out;

    char* ws = (char*)d_ws;
    unsigned short* y    = (unsigned short*)ws;                     // [16384][2048] 64 MB
    unsigned short* x_bf = (unsigned short*)(ws + 67108864ull);     // 16 MB
    unsigned short* wtT  = (unsigned short*)(ws + 83886080ull);     // [512][1024] 1 MB
    unsigned short* w2b  = (unsigned short*)(ws + 84934656ull);     // [512][1024] 1 MB
    unsigned short* Ucat = (unsigned short*)(ws + 85983232ull);     // [2048][1024] 4 MB
    unsigned short* W1c  = (unsigned short*)(ws + 90177536ull);     // [2048][512] 2 MB
    float*          b2   = (float*)(ws + 92274688ull);              // [2048] 8 KB
    float2*         G    = (float2*)(ws + 92282880ull);             // 640 B (1 KB)
    float2*         Dt   = (float2*)(ws + 92283904ull);             // 16 KB
    // high-water ~92.3 MB

    conv2_kernel<<<2048, 256, 0, stream>>>(x, x_bf, W_out, w2b);
    tpose_kernel<<<dim3(DMODEL / 32, DIM / 32), 256, 0, stream>>>(W_in, wtT);
    prep_kernel<<<1, 256, 0, stream>>>(rot, ent, G, Dt);
    buildU_kernel<<<DIM / 4, 256, 0, stream>>>(G, Dt, Ucat);
    // W1c[j,d] = sum_k Ucat[j,k] * W_in[k,d]
    gemm_bt<true, false><<<dim3(DMODEL / BN, 2 * DIM / BM), 256, 0, stream>>>(
        Ucat, wtT, nullptr, W1c, 2 * DIM, DMODEL, DIM, DIM);
    foldb_kernel<<<2 * DIM / 4, 256, 0, stream>>>(Ucat, b_in, b2);
    // y[t,j] = sum_d x[t,d] * W1c[j,d] + b2[j]
    gemm_bt<true, true><<<dim3(2 * DIM / BN, TOKENS / BM), 256, 0, stream>>>(
        x_bf, W1c, b2, y, TOKENS, 2 * DIM, DMODEL, DMODEL);
    sqnorm_kernel<<<TOKENS / 4, 256, 0, stream>>>(y);
    // out[t,d] = sum_k probs[t,k] * W_out[d,k] + b_out[d]   (probs lda=2048)
    gemm_bt<false, true><<<dim3(DMODEL / BN, TOKENS / BM), 256, 0, stream>>>(
        y, w2b, b_out, out, TOKENS, DMODEL, DIM, 2 * DIM);
    ln_kernel<<<TOKENS, 256, 0, stream>>>(out, ln_w, ln_b);
}

// Round 5
// 250.247 us; speedup vs baseline: 1.3249x; 1.0353x over previous
//
#include <hip/hip_runtime.h>
#include <cstdint>

#define TOKENS 16384
#define DMODEL 512
#define DIM    1024
#define NQ     10
#define NL     2
#define BM     128
#define BN     128
#define BK     32

typedef __bf16 bf16x8 __attribute__((ext_vector_type(8)));
typedef float  f32x4  __attribute__((ext_vector_type(4)));
typedef unsigned short u16x8 __attribute__((ext_vector_type(8)));

__device__ __forceinline__ float b2f(unsigned short h) {
    union { unsigned u; float f; } v; v.u = ((unsigned)h) << 16; return v.f;
}
__device__ __forceinline__ unsigned short f2b(float f) {
    unsigned u = __builtin_bit_cast(unsigned, f);
    return (unsigned short)((u + 0x7FFFu + ((u >> 16) & 1u)) >> 16);  // RNE
}
__device__ __forceinline__ float2 cmul(float2 a, float2 b) {
    return make_float2(a.x * b.x - a.y * b.y, a.x * b.y + a.y * b.x);
}
__device__ __forceinline__ float2 cadd(float2 a, float2 b) {
    return make_float2(a.x + b.x, a.y + b.y);
}
__device__ __forceinline__ void async_copy16(const void* g, void* l) {
    __builtin_amdgcn_global_load_lds((const __attribute__((address_space(1))) void*)g,
                                     (__attribute__((address_space(3))) void*)l, 16, 0, 0);
}

// ---------------------------------------------------------------------------
// conv2: fp32 -> bf16 for x and W_out; also zero-init n2 accumulator
// ---------------------------------------------------------------------------
__global__ __launch_bounds__(256)
void conv2_kernel(const float* __restrict__ x,  unsigned short* __restrict__ xb,
                  const float* __restrict__ w2, unsigned short* __restrict__ w2b,
                  float* __restrict__ n2) {
    const int NX4 = TOKENS * DMODEL / 4;   // 2097152
    const int NW4 = DMODEL * DIM / 4;      // 131072
    const int total = NX4 + NW4;
    int tid = blockIdx.x * 256 + threadIdx.x;
    if (tid < TOKENS / 4) *(float4*)&n2[tid * 4] = make_float4(0.f, 0.f, 0.f, 0.f);
    int stride = gridDim.x * blockDim.x;
    for (int i = tid; i < total; i += stride) {
        const float* s; unsigned short* d; int j;
        if (i < NX4) { s = x;  d = xb;  j = i; }
        else         { s = w2; d = w2b; j = i - NX4; }
        float4 v = *(const float4*)&s[(size_t)j * 4];
        ushort4 o;
        o.x = f2b(v.x); o.y = f2b(v.y); o.z = f2b(v.z); o.w = f2b(v.w);
        *(ushort4*)&d[(size_t)j * 4] = o;
    }
}

// ---------------------------------------------------------------------------
// tpose: W_in [1024,512] fp32 -> Wt [512,1024] bf16 (transposed)
// ---------------------------------------------------------------------------
__global__ __launch_bounds__(256)
void tpose_kernel(const float* __restrict__ W, unsigned short* __restrict__ Wt) {
    __shared__ float tile[32][33];
    const int tx = threadIdx.x & 31, ty = threadIdx.x >> 5;   // 32x8
    const int j0 = blockIdx.y * 32, d0 = blockIdx.x * 32;
    #pragma unroll
    for (int i = 0; i < 32; i += 8)
        tile[ty + i][tx] = W[(size_t)(j0 + ty + i) * DMODEL + d0 + tx];
    __syncthreads();
    #pragma unroll
    for (int i = 0; i < 32; i += 8)
        Wt[(size_t)(d0 + ty + i) * DIM + j0 + tx] = f2b(tile[tx][ty + i]);
}

// ---------------------------------------------------------------------------
// prep: fuse Rz*Ry*Rx into 2x2 complex gates, CZ diagonal lane-transposed:
//   Dt[l*1024 + (amp&15)*64 + (amp>>4)]
// ---------------------------------------------------------------------------
__global__ void prep_kernel(const float* __restrict__ rot, const float* __restrict__ ent,
                            float2* __restrict__ G, float2* __restrict__ Dt) {
    const int t = threadIdx.x;
    if (t < NL * NQ) {
        float tx = rot[t * 3 + 0] * 0.5f;
        float ty = rot[t * 3 + 1] * 0.5f;
        float tz = rot[t * 3 + 2] * 0.5f;
        float cx = cosf(tx), sx = sinf(tx);
        float cy = cosf(ty), sy = sinf(ty);
        float cz = cosf(tz), sz = sinf(tz);
        float2 rx00 = make_float2(cx, 0.f),  rx01 = make_float2(0.f, -sx);
        float2 rx10 = make_float2(0.f, -sx), rx11 = make_float2(cx, 0.f);
        float2 ry00 = make_float2(cy, 0.f),  ry01 = make_float2(-sy, 0.f);
        float2 ry10 = make_float2(sy, 0.f),  ry11 = make_float2(cy, 0.f);
        float2 m00 = cadd(cmul(ry00, rx00), cmul(ry01, rx10));
        float2 m01 = cadd(cmul(ry00, rx01), cmul(ry01, rx11));
        float2 m10 = cadd(cmul(ry10, rx00), cmul(ry11, rx10));
        float2 m11 = cadd(cmul(ry10, rx01), cmul(ry11, rx11));
        float2 e0 = make_float2(cz, -sz), e1 = make_float2(cz, sz);
        G[t * 4 + 0] = cmul(e0, m00);
        G[t * 4 + 1] = cmul(e0, m01);
        G[t * 4 + 2] = cmul(e1, m10);
        G[t * 4 + 3] = cmul(e1, m11);
    }
    float ef[NL * (NQ - 1)];
    #pragma unroll
    for (int i = 0; i < NL * (NQ - 1); i++) ef[i] = ent[i];
    for (int e = 0; e < 8; e++) {
        int idx = t + e * 256;
        int l = idx >> 10, amp = idx & (DIM - 1);
        float ang = 0.f;
        #pragma unroll
        for (int q = 0; q < NQ - 1; q++) {
            int both = ((amp >> (9 - q)) & 1) & ((amp >> (8 - q)) & 1);
            if (both) ang += ef[l * (NQ - 1) + q];
        }
        Dt[l * DIM + (amp & 15) * 64 + (amp >> 4)] = make_float2(cosf(ang), sinf(ang));
    }
}

// ---------------------------------------------------------------------------
// buildU: one wave per row c; transposed circuit applied to basis e_c gives
// row c of U. Rows stored INTERLEAVED: row 2c = Re U[c,:], row 2c+1 = Im.
// ---------------------------------------------------------------------------
__global__ __launch_bounds__(256)
void buildU_kernel(const float2* __restrict__ G, const float2* __restrict__ Dt,
                   unsigned short* __restrict__ U) {
    const int t = threadIdx.x, lane = t & 63;
    const int c = blockIdx.x * 4 + (t >> 6);

    float2 amp[16];
    #pragma unroll
    for (int r = 0; r < 16; r++)
        amp[r] = make_float2((lane * 16 + r == c) ? 1.f : 0.f, 0.f);

    #pragma unroll 1
    for (int li = 0; li < NL; li++) {
        const int l = NL - 1 - li;
        #pragma unroll
        for (int r = 0; r < 16; r++)
            amp[r] = cmul(amp[r], Dt[(size_t)l * DIM + r * 64 + lane]);
        const float2* Gl = G + (size_t)l * NQ * 4;
        #pragma unroll
        for (int qq = 0; qq < NQ; qq++) {
            const int q = 9 - qq;
            float2 u00 = Gl[q * 4 + 0], u10 = Gl[q * 4 + 1];   // transposed:
            float2 u01 = Gl[q * 4 + 2], u11 = Gl[q * 4 + 3];   // u01<->u10
            if (q >= 6) {
                const int S = 1 << (9 - q);
                #pragma unroll
                for (int r = 0; r < 16; r++) {
                    if (r & S) continue;
                    float2 a = amp[r], b = amp[r + S];
                    float2 n0, n1;
                    n0.x = u00.x * a.x - u00.y * a.y + u01.x * b.x - u01.y * b.y;
                    n0.y = u00.x * a.y + u00.y * a.x + u01.x * b.y + u01.y * b.x;
                    n1.x = u10.x * a.x - u10.y * a.y + u11.x * b.x - u11.y * b.y;
                    n1.y = u10.x * a.y + u10.y * a.x + u11.x * b.y + u11.y * b.x;
                    amp[r] = n0; amp[r + S] = n1;
                }
            } else {
                const int mask = 32 >> q;
                int bit = (lane >> (5 - q)) & 1;
                float2 ua = bit ? u11 : u00;
                float2 ub = bit ? u10 : u01;
                #pragma unroll
                for (int r = 0; r < 16; r++) {
                    float px = __shfl_xor(amp[r].x, mask, 64);
                    float py = __shfl_xor(amp[r].y, mask, 64);
                    float nx = ua.x * amp[r].x - ua.y * amp[r].y + ub.x * px - ub.y * py;
                    float ny = ua.x * amp[r].y + ua.y * amp[r].x + ub.x * py + ub.y * px;
                    amp[r] = make_float2(nx, ny);
                }
            }
        }
    }

    u16x8 o0, o1, p0, p1;
    #pragma unroll
    for (int r = 0; r < 8; r++) {
        o0[r] = f2b(amp[r].x);     o1[r] = f2b(amp[r + 8].x);
        p0[r] = f2b(amp[r].y);     p1[r] = f2b(amp[r + 8].y);
    }
    unsigned short* rowRe = U + (size_t)(2 * c) * DIM + lane * 16;
    unsigned short* rowIm = U + (size_t)(2 * c + 1) * DIM + lane * 16;
    *(u16x8*)rowRe = o0; *(u16x8*)(rowRe + 8) = o1;
    *(u16x8*)rowIm = p0; *(u16x8*)(rowIm + 8) = p1;
}

// ---------------------------------------------------------------------------
// foldB: b2[j] = sum_k Ucat[j,k] * b_in[k], one wave per j (interleaved order)
// ---------------------------------------------------------------------------
__global__ __launch_bounds__(256)
void foldb_kernel(const unsigned short* __restrict__ U, const float* __restrict__ bin,
                  float* __restrict__ b2) {
    const int lane = threadIdx.x & 63;
    const int j = blockIdx.x * 4 + (threadIdx.x >> 6);
    const unsigned short* row = U + (size_t)j * DIM;
    float acc = 0.f;
    #pragma unroll
    for (int i = 0; i < 16; i++) {
        int k = lane + i * 64;
        acc += b2f(row[k]) * bin[k];
    }
    #pragma unroll
    for (int m = 1; m < 64; m <<= 1) acc += __shfl_xor(acc, m, 64);
    if (lane == 0) b2[j] = acc;
}

// ---------------------------------------------------------------------------
// generic bf16 GEMM C=A*B^T (used for the U@W_in fold), bf16 out, no bias
// ---------------------------------------------------------------------------
__global__ __launch_bounds__(256)
void gemm_fold(const unsigned short* __restrict__ A, const unsigned short* __restrict__ B,
               unsigned short* __restrict__ C, int M, int N, int K, int lda) {
    __shared__ unsigned short lds_a[BM * BK];
    __shared__ unsigned short lds_b[BN * BK];
    const int t = threadIdx.x;
    const int wave = t >> 6, lane = t & 63;
    const int wm = wave >> 1, wn = wave & 1;
    const int bm0 = blockIdx.y * BM;
    const int bn0 = blockIdx.x * BN;

    f32x4 acc[4][4] = {};

    const int c0 = t, c1 = t + 256;
    const int r0 = c0 >> 2, g0 = (c0 & 3) ^ ((r0 >> 1) & 3);
    const int r1 = c1 >> 2, g1 = (c1 & 3) ^ ((r1 >> 1) & 3);

    for (int k0 = 0; k0 < K; k0 += BK) {
        async_copy16(A + (size_t)(bm0 + r0) * lda + k0 + g0 * 8, (char*)lds_a + wave * 1024);
        async_copy16(A + (size_t)(bm0 + r1) * lda + k0 + g1 * 8, (char*)lds_a + wave * 1024 + 4096);
        async_copy16(B + (size_t)(bn0 + r0) * K + k0 + g0 * 8, (char*)lds_b + wave * 1024);
        async_copy16(B + (size_t)(bn0 + r1) * K + k0 + g1 * 8, (char*)lds_b + wave * 1024 + 4096);
        __syncthreads();

        bf16x8 af[4], bfr[4];
        #pragma unroll
        for (int i = 0; i < 4; i++) {
            int row = wm * 64 + i * 16 + (lane & 15);
            int slot = (lane >> 4) ^ ((row >> 1) & 3);
            af[i] = *(const bf16x8*)&lds_a[row * BK + slot * 8];
            int nrow = wn * 64 + i * 16 + (lane & 15);
            int nslot = (lane >> 4) ^ ((nrow >> 1) & 3);
            bfr[i] = *(const bf16x8*)&lds_b[nrow * BK + nslot * 8];
        }
        #pragma unroll
        for (int i = 0; i < 4; i++)
            #pragma unroll
            for (int j = 0; j < 4; j++)
                acc[i][j] = __builtin_amdgcn_mfma_f32_16x16x32_bf16(af[i], bfr[j], acc[i][j], 0, 0, 0);
        __syncthreads();
    }

    #pragma unroll
    for (int i = 0; i < 4; i++)
        #pragma unroll
        for (int j = 0; j < 4; j++) {
            int col = bn0 + wn * 64 + j * 16 + (lane & 15);
            #pragma unroll
            for (int r = 0; r < 4; r++) {
                int row = bm0 + wm * 64 + i * 16 + (lane >> 4) * 4 + r;
                C[(size_t)row * N + col] = f2b(acc[i][j][r]);
            }
        }
}

// ---------------------------------------------------------------------------
// gemm1: y = x_bf @ W1c^T + b2 with INTERLEAVED re/im cols. Epilogue squares,
// pair-sums (p = re^2+im^2), writes p bf16 [TOKENS][DIM], and atomically
// accumulates n2[row] = sum(val^2) (= ||xq||^2 by unitarity).
// ---------------------------------------------------------------------------
__global__ __launch_bounds__(256)
void gemm1_kernel(const unsigned short* __restrict__ A, const unsigned short* __restrict__ B,
                  const float* __restrict__ bias, unsigned short* __restrict__ P,
                  float* __restrict__ n2) {
    const int N = 2 * DIM, K = DMODEL;
    __shared__ unsigned short lds_a[BM * BK];
    __shared__ unsigned short lds_b[BN * BK];
    const int t = threadIdx.x;
    const int wave = t >> 6, lane = t & 63;
    const int wm = wave >> 1, wn = wave & 1;
    const int bm0 = blockIdx.y * BM;
    const int bn0 = blockIdx.x * BN;

    f32x4 acc[4][4] = {};

    const int c0 = t, c1 = t + 256;
    const int r0 = c0 >> 2, g0 = (c0 & 3) ^ ((r0 >> 1) & 3);
    const int r1 = c1 >> 2, g1 = (c1 & 3) ^ ((r1 >> 1) & 3);

    for (int k0 = 0; k0 < K; k0 += BK) {
        async_copy16(A + (size_t)(bm0 + r0) * K + k0 + g0 * 8, (char*)lds_a + wave * 1024);
        async_copy16(A + (size_t)(bm0 + r1) * K + k0 + g1 * 8, (char*)lds_a + wave * 1024 + 4096);
        async_copy16(B + (size_t)(bn0 + r0) * K + k0 + g0 * 8, (char*)lds_b + wave * 1024);
        async_copy16(B + (size_t)(bn0 + r1) * K + k0 + g1 * 8, (char*)lds_b + wave * 1024 + 4096);
        __syncthreads();

        bf16x8 af[4], bfr[4];
        #pragma unroll
        for (int i = 0; i < 4; i++) {
            int row = wm * 64 + i * 16 + (lane & 15);
            int slot = (lane >> 4) ^ ((row >> 1) & 3);
            af[i] = *(const bf16x8*)&lds_a[row * BK + slot * 8];
            int nrow = wn * 64 + i * 16 + (lane & 15);
            int nslot = (lane >> 4) ^ ((nrow >> 1) & 3);
            bfr[i] = *(const bf16x8*)&lds_b[nrow * BK + nslot * 8];
        }
        #pragma unroll
        for (int i = 0; i < 4; i++)
            #pragma unroll
            for (int j = 0; j < 4; j++)
                acc[i][j] = __builtin_amdgcn_mfma_f32_16x16x32_bf16(af[i], bfr[j], acc[i][j], 0, 0, 0);
        __syncthreads();
    }

    // epilogue: p = re^2+im^2 via lane-pair shuffle; n2 partials via atomics
    #pragma unroll
    for (int i = 0; i < 4; i++) {
        #pragma unroll
        for (int r = 0; r < 4; r++) {
            int row = bm0 + wm * 64 + i * 16 + (lane >> 4) * 4 + r;
            float rs = 0.f;
            #pragma unroll
            for (int j = 0; j < 4; j++) {
                int col = bn0 + wn * 64 + j * 16 + (lane & 15);
                float val = acc[i][j][r] + bias[col];
                float v2 = val * val;
                rs += v2;
                float v2p = v2 + __shfl_xor(v2, 1, 64);
                if (!(lane & 1))
                    P[(size_t)row * DIM + (col >> 1)] = f2b(v2p);
            }
            rs += __shfl_xor(rs, 1, 64);
            rs += __shfl_xor(rs, 2, 64);
            rs += __shfl_xor(rs, 4, 64);
            rs += __shfl_xor(rs, 8, 64);
            if ((lane & 15) == 0) atomicAdd(&n2[row], rs);
        }
    }
}

// ---------------------------------------------------------------------------
// gemm2_ln: out = LayerNorm( (p/n2) @ W_out^T + b_out ) * ln_w + ln_b
// BM=32 x BN=512 (full d_model per block) so LN fuses into the epilogue.
// 4 waves, each owns 128 cols; acc[2][8] per lane.
// ---------------------------------------------------------------------------
__global__ __launch_bounds__(256)
void gemm2_ln_kernel(const unsigned short* __restrict__ A,   // p [TOKENS][DIM]
                     const unsigned short* __restrict__ B,   // w2b [DMODEL][DIM]
                     const float* __restrict__ bias, const float* __restrict__ n2,
                     const float* __restrict__ lw, const float* __restrict__ lb,
                     float* __restrict__ out) {
    __shared__ unsigned short lds_a[32 * BK];      // 2 KB
    __shared__ unsigned short lds_b[512 * BK];     // 32 KB
    __shared__ float redS[4][32], redQ[4][32];
    __shared__ float muS[32], rsS[32];
    const int t = threadIdx.x, wave = t >> 6, lane = t & 63;
    const int bm0 = blockIdx.x * 32;

    f32x4 acc[2][8] = {};

    const int ra = t >> 2, ga = (t & 3) ^ ((ra >> 1) & 3);   // A chunks (t<128)

    for (int k0 = 0; k0 < DIM; k0 += BK) {
        if (wave < 2)
            async_copy16(A + (size_t)(bm0 + ra) * DIM + k0 + ga * 8,
                         (char*)lds_a + wave * 1024);
        #pragma unroll
        for (int s = 0; s < 8; s++) {
            int c = t + s * 256;
            int r = c >> 2, g = (c & 3) ^ ((r >> 1) & 3);
            async_copy16(B + (size_t)r * DIM + k0 + g * 8,
                         (char*)lds_b + s * 4096 + wave * 1024);
        }
        __syncthreads();

        bf16x8 af[2], bfr[8];
        #pragma unroll
        for (int i = 0; i < 2; i++) {
            int row = i * 16 + (lane & 15);
            int slot = (lane >> 4) ^ ((row >> 1) & 3);
            af[i] = *(const bf16x8*)&lds_a[row * BK + slot * 8];
        }
        #pragma unroll
        for (int j = 0; j < 8; j++) {
            int nrow = wave * 128 + j * 16 + (lane & 15);
            int nslot = (lane >> 4) ^ ((nrow >> 1) & 3);
            bfr[j] = *(const bf16x8*)&lds_b[nrow * BK + nslot * 8];
        }
        #pragma unroll
        for (int i = 0; i < 2; i++)
            #pragma unroll
            for (int j = 0; j < 8; j++)
                acc[i][j] = __builtin_amdgcn_mfma_f32_16x16x32_bf16(af[i], bfr[j], acc[i][j], 0, 0, 0);
        __syncthreads();
    }

    // ---- epilogue: scale by 1/n2, +bias, LN over the 512-wide row ----
    const int colb = wave * 128;
    float nn[8];
    #pragma unroll
    for (int i = 0; i < 2; i++)
        #pragma unroll
        for (int r = 0; r < 4; r++) {
            int rl = i * 16 + (lane >> 4) * 4 + r;
            nn[i * 4 + r] = 1.0f / fmaxf(n2[bm0 + rl], 1e-24f);
        }
    float pS[8], pQ[8];
    #pragma unroll
    for (int i = 0; i < 2; i++)
        #pragma unroll
        for (int r = 0; r < 4; r++) {
            float s = 0.f, q = 0.f;
            #pragma unroll
            for (int j = 0; j < 8; j++) {
                int col = colb + j * 16 + (lane & 15);
                float val = acc[i][j][r] * nn[i * 4 + r] + bias[col];
                acc[i][j][r] = val;
                s += val; q += val * val;
            }
            s += __shfl_xor(s, 1, 64); q += __shfl_xor(q, 1, 64);
            s += __shfl_xor(s, 2, 64); q += __shfl_xor(q, 2, 64);
            s += __shfl_xor(s, 4, 64); q += __shfl_xor(q, 4, 64);
            s += __shfl_xor(s, 8, 64); q += __shfl_xor(q, 8, 64);
            pS[i * 4 + r] = s; pQ[i * 4 + r] = q;
        }
    if ((lane & 15) == 0) {
        #pragma unroll
        for (int i = 0; i < 2; i++)
            #pragma unroll
            for (int r = 0; r < 4; r++) {
                int rl = i * 16 + (lane >> 4) * 4 + r;
                redS[wave][rl] = pS[i * 4 + r];
                redQ[wave][rl] = pQ[i * 4 + r];
            }
    }
    __syncthreads();
    if (t < 32) {
        float s = redS[0][t] + redS[1][t] + redS[2][t] + redS[3][t];
        float q = redQ[0][t] + redQ[1][t] + redQ[2][t] + redQ[3][t];
        float mu = s * (1.0f / DMODEL);
        float var = q * (1.0f / DMODEL) - mu * mu;
        muS[t] = mu;
        rsS[t] = rsqrtf(var + 1e-5f);
    }
    __syncthreads();
    #pragma unroll
    for (int i = 0; i < 2; i++)
        #pragma unroll
        for (int j = 0; j < 8; j++) {
            int col = colb + j * 16 + (lane & 15);
            float w = lw[col], bb = lb[col];
            #pragma unroll
            for (int r = 0; r < 4; r++) {
                int rl = i * 16 + (lane >> 4) * 4 + r;
                out[(size_t)(bm0 + rl) * DMODEL + col] =
                    (acc[i][j][r] - muS[rl]) * rsS[rl] * w + bb;
            }
        }
}

extern "C" void kernel_launch(void* const* d_in, const int* in_sizes, int n_in,
                              void* d_out, int out_size, void* d_ws, size_t ws_size,
                              hipStream_t stream) {
    (void)in_sizes; (void)n_in; (void)out_size; (void)ws_size;
    const float* x     = (const float*)d_in[0];
    const float* W_in  = (const float*)d_in[1];
    const float* b_in  = (const float*)d_in[2];
    const float* W_out = (const float*)d_in[3];
    const float* b_out = (const float*)d_in[4];
    const float* rot   = (const float*)d_in[5];
    const float* ent   = (const float*)d_in[6];
    const float* ln_w  = (const float*)d_in[7];
    const float* ln_b  = (const float*)d_in[8];
    float* out = (float*)d_out;

    char* ws = (char*)d_ws;
    unsigned short* p    = (unsigned short*)ws;                     // [16384][1024] 32 MB
    unsigned short* x_bf = (unsigned short*)(ws + 33554432ull);     // 16 MB
    unsigned short* wtT  = (unsigned short*)(ws + 50331648ull);     // [512][1024] 1 MB
    unsigned short* w2b  = (unsigned short*)(ws + 51380224ull);     // [512][1024] 1 MB
    unsigned short* Ucat = (unsigned short*)(ws + 52428800ull);     // [2048][1024] 4 MB
    unsigned short* W1c  = (unsigned short*)(ws + 56623104ull);     // [2048][512] 2 MB
    float*          b2   = (float*)(ws + 58720256ull);              // [2048] 8 KB
    float2*         G    = (float2*)(ws + 58728448ull);             // 640 B (1 KB)
    float2*         Dt   = (float2*)(ws + 58729472ull);             // 16 KB
    float*          n2   = (float*)(ws + 58745856ull);              // [16384] 64 KB
    // high-water ~56.1 MB

    conv2_kernel<<<2048, 256, 0, stream>>>(x, x_bf, W_out, w2b, n2);
    tpose_kernel<<<dim3(DMODEL / 32, DIM / 32), 256, 0, stream>>>(W_in, wtT);
    prep_kernel<<<1, 256, 0, stream>>>(rot, ent, G, Dt);
    buildU_kernel<<<DIM / 4, 256, 0, stream>>>(G, Dt, Ucat);
    // W1c[j,d] = sum_k Ucat[j,k] * W_in[k,d]   (rows j interleaved re/im)
    gemm_fold<<<dim3(DMODEL / BN, 2 * DIM / BM), 256, 0, stream>>>(
        Ucat, wtT, W1c, 2 * DIM, DMODEL, DIM, DIM);
    foldb_kernel<<<2 * DIM / 4, 256, 0, stream>>>(Ucat, b_in, b2);
    // p[t,k] = |y_k|^2, n2[t] = ||xq||^2
    gemm1_kernel<<<dim3(2 * DIM / BN, TOKENS / BM), 256, 0, stream>>>(
        x_bf, W1c, b2, p, n2);
    // out = LN( (p/n2) @ W_out^T + b_out )
    gemm2_ln_kernel<<<TOKENS / 32, 256, 0, stream>>>(
        p, w2b, b_out, n2, ln_w, ln_b, out);
}